// Round 2
// baseline (776.410 us; speedup 1.0000x reference)
//
#include <hip/hip_runtime.h>
#include <stdint.h>

typedef uint32_t u32;
typedef unsigned long long u64;

#define TCAP 1048576        // triplet capacity (expected T ~= 720k +- 3k)
#define RX_CHUNK 4096
#define SCAN_TILE 2048

// scal[] slots (device scalars)
#define S_T 0
#define S_MAXT 1
#define S_DSTAR 2
#define S_NEED 3
#define S_TKEPT 4
#define S_U 5

// ---------------- generic exclusive scan ----------------
__global__ void scan_l1(const u32* __restrict__ in, u32* __restrict__ out,
                        u32* __restrict__ bsums, int n){
  __shared__ u32 sh[256];
  int tid = threadIdx.x;
  int base = blockIdx.x * SCAN_TILE + tid * 8;
  u32 v[8]; u32 s = 0;
#pragma unroll
  for(int k=0;k<8;k++){ u32 xv = (base+k<n) ? in[base+k] : 0u; v[k]=s; s+=xv; }
  sh[tid]=s; __syncthreads();
  for(int o=1;o<256;o<<=1){
    u32 y = (tid>=o) ? sh[tid-o] : 0u;
    __syncthreads();
    sh[tid] += y;
    __syncthreads();
  }
  u32 excl = (tid==0) ? 0u : sh[tid-1];
  if(bsums != nullptr && tid==255) bsums[blockIdx.x] = sh[255];
#pragma unroll
  for(int k=0;k<8;k++){ if(base+k<n) out[base+k] = excl + v[k]; }
}

__global__ void scan_add(u32* out, const u32* __restrict__ bsums, int n){
  int i = blockIdx.x*256 + threadIdx.x;
  if(i<n) out[i] += bsums[i/SCAN_TILE];
}

// ---------------- stable 8-bit radix pass ----------------
__global__ void rx_hist(const u32* __restrict__ keys, u32* __restrict__ hist,
                        int B, int shift, int hostN, const int* __restrict__ dN){
  __shared__ u32 h[256];
  int n = (hostN>=0) ? hostN : dN[S_T];
  h[threadIdx.x]=0u; __syncthreads();
  int base = blockIdx.x*RX_CHUNK;
  for(int k=threadIdx.x;k<RX_CHUNK;k+=256){
    int p = base+k;
    if(p<n){ u32 d=(keys[p]>>shift)&255u; atomicAdd(&h[d],1u); }
  }
  __syncthreads();
  hist[threadIdx.x*B + blockIdx.x] = h[threadIdx.x]; // digit-major layout
}

// one wave per block; processes its chunk in index order -> stable
__global__ void rx_scatter(const u32* __restrict__ keys, const u32* __restrict__ pays,
                           u32* __restrict__ okeys, u32* __restrict__ opays,
                           const u32* __restrict__ basep, int B, int shift,
                           int hostN, const int* __restrict__ dN){
  __shared__ u32 cnt[256];
  int n = (hostN>=0) ? hostN : dN[S_T];
  int lane = threadIdx.x;
  for(int i=lane;i<256;i+=64) cnt[i]=0u;
  __syncthreads();
  int start = blockIdx.x*RX_CHUNK;
  for(int it=0; it<RX_CHUNK/64; ++it){
    int p = start + it*64 + lane;
    bool act = (p<n);
    u32 key = act ? keys[p] : 0u;
    u32 pay = act ? (pays ? pays[p] : (u32)p) : 0u;
    u32 dig = (key>>shift)&255u;
    u64 m = __ballot(act ? 1 : 0);          // restrict groups to active lanes
    for(int bb=0;bb<8;bb++){
      u64 bl = __ballot((int)((dig>>bb)&1u));
      m &= ((dig>>bb)&1u) ? bl : ~bl;
    }
    u64 lt = (1ull<<lane) - 1ull;
    u32 rb = (u32)__popcll(m & lt);          // stable rank within this tile
    u32 c = cnt[dig];                        // count from earlier tiles
    if(act && rb==0u) atomicAdd(&cnt[dig], (u32)__popcll(m));
    __syncthreads();
    if(act){
      u32 pos = basep[dig*B + blockIdx.x] + c + rb;
      okeys[pos]=key; opays[pos]=pay;
    }
  }
}

// ---------------- pipeline kernels ----------------
__global__ void k_gather_edges(const u32* __restrict__ skeys, const u32* __restrict__ sperm,
                               const u32* __restrict__ tgt, u32* s0, u32* t0, int E){
  int j = blockIdx.x*256+threadIdx.x;
  if(j<E){ s0[j]=skeys[j]; t0[j]=tgt[sperm[j]]; }
}

__global__ void k_hist_vals(const u32* __restrict__ vals, u32* cnt, int n){
  int i=blockIdx.x*256+threadIdx.x;
  if(i<n) atomicAdd(&cnt[vals[i]],1u);
}

__global__ void k_calc_cnts(const u32* __restrict__ s0, const u32* __restrict__ rp_tgt,
                            u32* cnts, int E){
  int e=blockIdx.x*256+threadIdx.x;
  if(e>E) return;
  if(e==E){ cnts[e]=0u; return; }
  u32 s=s0[e];
  cnts[e]=rp_tgt[s+1]-rp_tgt[s];
}

__global__ void k_set_T(const u32* __restrict__ start, int E, int* scal){
  int t=(int)start[E];
  scal[S_T]= (t<TCAP) ? t : TCAP;
}

__global__ void k_gen_tri(const u32* __restrict__ s0, const u32* __restrict__ t0,
                          const u32* __restrict__ ordT, const u32* __restrict__ rp_tgt,
                          const u32* __restrict__ cnts, const u32* __restrict__ start,
                          u32* tri0, u32* tri1, u32* tri2, int E, int* scal){
  int e=blockIdx.x*256+threadIdx.x;
  if(e>=E) return;
  u32 s=s0[e], te=t0[e];
  u32 lb=rp_tgt[s], c=cnts[e], st=start[e];
  int mx=-1;
  for(u32 i=0;i<c;i++){
    u32 idx=st+i; if(idx>=TCAP) break;
    u32 h=ordT[lb+i];
    u32 a=s0[h], mm=t0[h];
    tri0[idx]=a; tri1[idx]=mm; tri2[idx]=te;
    int loc=(int)(a>mm?a:mm); loc = loc>(int)te?loc:(int)te;
    if(loc>mx) mx=loc;
  }
  if(mx>=0) atomicMax(&scal[S_MAXT], mx);
}

__global__ void k_deg(const u32* __restrict__ t0g, const u32* __restrict__ t1g,
                      const u32* __restrict__ t2g, u32* deg, const int* __restrict__ scal){
  int p=blockIdx.x*256+threadIdx.x;
  if(p>=scal[S_T]) return;
  atomicAdd(&deg[t0g[p]],1u);
  atomicAdd(&deg[t1g[p]],1u);
  atomicAdd(&deg[t2g[p]],1u);
}

__global__ void k_gather_tri(const u32* __restrict__ skeys, const u32* __restrict__ sperm,
                             const u32* __restrict__ t1g, const u32* __restrict__ t2g,
                             u32* t0s, u32* t1s, u32* t2s, const int* __restrict__ scal){
  int p=blockIdx.x*256+threadIdx.x;
  if(p>=scal[S_T]) return;
  u32 pp=sperm[p];
  t0s[p]=skeys[p]; t1s[p]=t1g[pp]; t2s[p]=t2g[pp];
}

__global__ void k_degHist(const u32* __restrict__ deg, u32* dh, int NN, const int* __restrict__ scal){
  int v=blockIdx.x*256+threadIdx.x;
  if(v>=NN || v>scal[S_MAXT]) return;
  u32 d=deg[v]; if(d>65535u)d=65535u;
  atomicAdd(&dh[d],1u);
}

__global__ void k_find_dstar(const u32* __restrict__ dh, const u32* __restrict__ dhs, int* scal){
  int d=blockIdx.x*256+threadIdx.x;
  if(d>=65536) return;
  long long kk=(((long long)scal[S_MAXT])+1)>>1;
  if(kk==0){ if(d==0){ scal[S_DSTAR]=-1; scal[S_NEED]=0; } return; }
  long long cum=(long long)dhs[d], h=(long long)dh[d];
  if(cum<=kk-1 && kk-1<cum+h){ scal[S_DSTAR]=d; scal[S_NEED]=(int)(kk-cum); }
}

__global__ void k_ef(const u32* __restrict__ deg, u32* ef, int NN, const int* __restrict__ scal){
  int v=blockIdx.x*256+threadIdx.x;
  if(v>NN) return;
  ef[v] = (v<NN && (int)deg[v]==scal[S_DSTAR]) ? 1u:0u;
}

__global__ void k_keep(const u32* __restrict__ deg, const u32* __restrict__ rankEq,
                       u32* keep, int NN, const int* __restrict__ scal){
  int v=blockIdx.x*256+threadIdx.x;
  if(v>=NN) return;
  int d=(int)deg[v]; int ds=scal[S_DSTAR]; int need=scal[S_NEED];
  u32 kp=1u;
  if(d<ds) kp=0u;
  else if(d==ds && (int)rankEq[v]<need) kp=0u;
  keep[v]=kp;
}

__global__ void k_mask(const u32* __restrict__ t0s, const u32* __restrict__ t1s,
                       const u32* __restrict__ t2s, const u32* __restrict__ keep,
                       u32* mask, const int* __restrict__ scal){
  int p=blockIdx.x*256+threadIdx.x;
  if(p>TCAP) return;
  u32 m=0u;
  if(p<scal[S_T]) m = keep[t0s[p]] & keep[t1s[p]] & keep[t2s[p]];
  mask[p]=m;
}

__global__ void k_set_tkept(const u32* __restrict__ msPos, int* scal){
  scal[S_TKEPT]=(int)msPos[scal[S_T]];
}

__global__ void k_compact(const u32* __restrict__ t0s, const u32* __restrict__ t1s,
                          const u32* __restrict__ t2s, const u32* __restrict__ mask,
                          const u32* __restrict__ msPos, u32* ks,u32* km,u32* kt,
                          const int* __restrict__ scal){
  int p=blockIdx.x*256+threadIdx.x;
  if(p>=scal[S_T] || !mask[p]) return;
  u32 q=msPos[p];
  ks[q]=t0s[p]; km[q]=t1s[p]; kt[q]=t2s[p];
}

__global__ void k_heads(const u32* __restrict__ ks, u32* hf, const int* __restrict__ scal){
  int q=blockIdx.x*256+threadIdx.x;
  if(q>TCAP) return;
  u32 f=0u;
  int Tk=scal[S_TKEPT];
  if(q<Tk) f = (q==0 || ks[q]!=ks[q-1]) ? 1u:0u;
  hf[q]=f;
}

__global__ void k_set_U(const u32* __restrict__ hs, u32* gs, int* scal){
  int Tk=scal[S_TKEPT];
  int U=(int)hs[Tk];
  scal[S_U]=U;
  gs[U]=(u32)Tk;
}

__global__ void k_gs(const u32* __restrict__ hf, const u32* __restrict__ hs,
                     u32* gs, const int* __restrict__ scal){
  int q=blockIdx.x*256+threadIdx.x;
  if(q>=scal[S_TKEPT]) return;
  if(hf[q]) gs[hs[q+1]-1u]=(u32)q;
}

__global__ void k_present(const u32* __restrict__ ks,const u32* __restrict__ km,
                          const u32* __restrict__ kt, u32* present, const int* __restrict__ scal){
  int q=blockIdx.x*256+threadIdx.x;
  if(q>=scal[S_TKEPT]) return;
  present[ks[q]]=1u; present[km[q]]=1u; present[kt[q]]=1u;
}

__global__ void k_write_ei(const u32* __restrict__ ks,const u32* __restrict__ km,
                           const u32* __restrict__ kt, const u32* __restrict__ newid,
                           float* out, const int* __restrict__ scal, int out_size){
  int q=blockIdx.x*256+threadIdx.x;
  int Tk=scal[S_TKEPT];
  if(q>=Tk) return;
  int bs=scal[S_U]*64;
  int i0=bs+q, i1=bs+Tk+q, i2=bs+2*Tk+q;
  if(i0<out_size) out[i0]=(float)newid[ks[q]];
  if(i1<out_size) out[i1]=(float)newid[km[q]];
  if(i2<out_size) out[i2]=(float)newid[kt[q]];
}

// per-group: sum gathered x rows, then one 64x192 matvec
__global__ void k_xnew(const float* __restrict__ x, const float* __restrict__ W,
                       const float* __restrict__ b, const u32* __restrict__ ks,
                       const u32* __restrict__ km, const u32* __restrict__ kt,
                       const u32* __restrict__ gs, float* out,
                       const int* __restrict__ scal, int out_size){
  int g=blockIdx.x;
  if(g>=scal[S_U]) return;
  int tid=threadIdx.x;
  u32 q0=gs[g], q1=gs[g+1];
  float a0=0.f,a1=0.f,a2=0.f;
  for(u32 q=q0;q<q1;q++){
    a0+=x[(size_t)ks[q]*64+tid];
    a1+=x[(size_t)km[q]*64+tid];
    a2+=x[(size_t)kt[q]*64+tid];
  }
  __shared__ float sh[192];
  sh[tid]=a0; sh[64+tid]=a1; sh[128+tid]=a2;
  __syncthreads();
  float acc=0.f;
  for(int ii=0;ii<64;ii++){
    const float* wr=&W[((size_t)tid*64+(size_t)ii)*3];
    acc += wr[0]*sh[ii]+wr[1]*sh[64+ii]+wr[2]*sh[128+ii];
  }
  float invc=1.f/(float)(q1-q0);
  int oi=g*64+tid;
  if(oi<out_size) out[oi]=b[tid]+acc*invc;
}

// ---------------- host helpers ----------------
static inline void scan_ex(hipStream_t st, const u32* in, u32* out, int n, u32* bsums){
  int nb=(n+SCAN_TILE-1)/SCAN_TILE;
  if(nb<=1){ scan_l1<<<1,256,0,st>>>(in,out,(u32*)nullptr,n); return; }
  scan_l1<<<nb,256,0,st>>>(in,out,bsums,n);
  scan_l1<<<1,256,0,st>>>(bsums,bsums,(u32*)nullptr,nb);
  scan_add<<<(n+255)/256,256,0,st>>>(out,bsums,n);
}

static inline void rx_pass(hipStream_t st,const u32* kin,const u32* pin,u32* kout,u32* pout,
                           u32* hist,u32* bsums,int B,int shift,int hostN,const int* dN){
  rx_hist<<<B,256,0,st>>>(kin,hist,B,shift,hostN,dN);
  scan_ex(st,hist,hist,256*B,bsums);
  rx_scatter<<<B,64,0,st>>>(kin,pin,kout,pout,hist,B,shift,hostN,dN);
}

extern "C" void kernel_launch(void* const* d_in, const int* in_sizes, int n_in,
                              void* d_out, int out_size, void* d_ws, size_t ws_size,
                              hipStream_t stream){
  const float* x = (const float*)d_in[0];
  const int*   ei = (const int*)d_in[1];
  const float* W = (const float*)d_in[2];
  const float* b = (const float*)d_in[3];
  int NN = in_sizes[0]/64;
  int E  = in_sizes[1]/2;
  const u32* src=(const u32*)ei;
  const u32* tgt=(const u32*)(ei+E);

  // bump allocator over d_ws (256B aligned)
  char* base=(char*)d_ws; size_t off=0;
  auto alloc=[&](size_t nInts)->u32*{
    u32* p=(u32*)(base+off);
    off += ( (nInts*4 + 255) & ~(size_t)255 );
    return p;
  };
  int* scal=(int*)alloc(64);
  u32* keyA=alloc(TCAP+1); u32* payA=alloc(TCAP+1);
  u32* keyB=alloc(TCAP+1); u32* payB=alloc(TCAP+1);
  u32* s0=alloc(E); u32* t0=alloc(E);
  u32* cntNode=alloc(NN+1); u32* rp_tgt=alloc(NN+1);
  u32* cnts=alloc(E+1); u32* start=alloc(E+1);
  u32* tri0g=alloc(TCAP); u32* tri1g=alloc(TCAP); u32* tri2g=alloc(TCAP);
  u32* tri0s=alloc(TCAP); u32* tri1s=alloc(TCAP); u32* tri2s=alloc(TCAP);
  u32* deg=alloc(NN); u32* degHist=alloc(65536); u32* degHistScan=alloc(65536);
  u32* ef=alloc(NN+1); u32* rankEq=alloc(NN+1); u32* keep=alloc(NN);
  u32* present=alloc(NN+1); u32* newid=alloc(NN+1); u32* gs=alloc(NN+2);
  u32* rxhist=alloc(256*(TCAP/RX_CHUNK));
  u32* bsums=alloc(4096);
  if(off > ws_size) return; // workspace too small -> bail (will fail loudly)

  // aliases (buffers free by the time these are used)
  u32* mask=keyB; u32* msPos=payB; u32* hf=keyA; u32* hs=payA;
  u32* ks=tri0g; u32* km=tri1g; u32* kt=tri2g;

  int gE=(E+255)/256, gE1=(E+256)/256;
  int gNN=(NN+255)/256, gNN1=(NN+256)/256;
  int gTC=(TCAP+255)/256, gTC1=(TCAP+256)/256;
  int BE=(E+RX_CHUNK-1)/RX_CHUNK;
  int BT=TCAP/RX_CHUNK;

  hipMemsetAsync(scal,0,256,stream);

  // --- sort 1: stable sort edges by src (keys<2^16 -> 2 passes) ---
  rx_pass(stream,src,nullptr,keyB,payB,rxhist,bsums,BE,0,E,scal);
  rx_pass(stream,keyB,payB,keyA,payA,rxhist,bsums,BE,8,E,scal);
  k_gather_edges<<<gE,256,0,stream>>>(keyA,payA,tgt,s0,t0,E);

  // --- rp_tgt: histogram CSR over tgt (== searchsorted lb/ub) ---
  hipMemsetAsync(cntNode,0,(size_t)(NN+1)*4,stream);
  k_hist_vals<<<gE,256,0,stream>>>(t0,cntNode,E);
  scan_ex(stream,cntNode,rp_tgt,NN+1,bsums);

  // --- sort 2: stable argsort of t0 -> ordT (payA) ---
  rx_pass(stream,t0,nullptr,keyB,payB,rxhist,bsums,BE,0,E,scal);
  rx_pass(stream,keyB,payB,keyA,payA,rxhist,bsums,BE,8,E,scal);

  // --- counts / start / T ---
  k_calc_cnts<<<gE1,256,0,stream>>>(s0,rp_tgt,cnts,E);
  scan_ex(stream,cnts,start,E+1,bsums);
  k_set_T<<<1,1,0,stream>>>(start,E,scal);

  // --- generate triplets (natural (e,h) order) + maxTri ---
  k_gen_tri<<<gE,256,0,stream>>>(s0,t0,payA,rp_tgt,cnts,start,tri0g,tri1g,tri2g,E,scal);

  // --- deg = bincount(tri.ravel()) ---
  hipMemsetAsync(deg,0,(size_t)NN*4,stream);
  k_deg<<<gTC,256,0,stream>>>(tri0g,tri1g,tri2g,deg,scal);

  // --- sort 3: stable sort triplets by tri[0] ---
  rx_pass(stream,tri0g,nullptr,keyB,payB,rxhist,bsums,BT,0,-1,scal);
  rx_pass(stream,keyB,payB,keyA,payA,rxhist,bsums,BT,8,-1,scal);
  k_gather_tri<<<gTC,256,0,stream>>>(keyA,payA,tri1g,tri2g,tri0s,tri1s,tri2s,scal);

  // --- degree-based prune selection (k = (maxTri+1)/2 smallest (deg,id)) ---
  hipMemsetAsync(degHist,0,(size_t)65536*4,stream);
  k_degHist<<<gNN,256,0,stream>>>(deg,degHist,NN,scal);
  scan_ex(stream,degHist,degHistScan,65536,bsums);
  k_find_dstar<<<256,256,0,stream>>>(degHist,degHistScan,scal);
  k_ef<<<gNN1,256,0,stream>>>(deg,ef,NN,scal);
  scan_ex(stream,ef,rankEq,NN+1,bsums);
  k_keep<<<gNN,256,0,stream>>>(deg,rankEq,keep,NN,scal);

  // --- mask + compact kept triplets (order preserved) ---
  k_mask<<<gTC1,256,0,stream>>>(tri0s,tri1s,tri2s,keep,mask,scal);
  scan_ex(stream,mask,msPos,TCAP+1,bsums);
  k_set_tkept<<<1,1,0,stream>>>(msPos,scal);
  k_compact<<<gTC,256,0,stream>>>(tri0s,tri1s,tri2s,mask,msPos,ks,km,kt,scal);

  // --- group boundaries over kept srcs (uniq/inv/cnt) ---
  k_heads<<<gTC1,256,0,stream>>>(ks,hf,scal);
  scan_ex(stream,hf,hs,TCAP+1,bsums);
  k_set_U<<<1,1,0,stream>>>(hs,gs,scal);
  k_gs<<<gTC,256,0,stream>>>(hf,hs,gs,scal);

  // --- newid = rank among distinct node values in tri_kept ---
  hipMemsetAsync(present,0,(size_t)(NN+1)*4,stream);
  k_present<<<gTC,256,0,stream>>>(ks,km,kt,present,scal);
  scan_ex(stream,present,newid,NN+1,bsums);

  // --- outputs ---
  float* outF=(float*)d_out;
  k_write_ei<<<gTC,256,0,stream>>>(ks,km,kt,newid,outF,scal,out_size);
  k_xnew<<<NN,64,0,stream>>>(x,W,b,ks,km,kt,gs,outF,scal,out_size);
}

// Round 3
// 451.332 us; speedup vs baseline: 1.7203x; 1.7203x over previous
//
#include <hip/hip_runtime.h>
#include <stdint.h>

typedef uint32_t u32;
typedef unsigned long long u64;

#define TCAP 1048576        // triplet capacity (expected T ~= 720k)
#define RX_CHUNK 512
#define LB_TILE 2048

// scal[] slots (device scalars)
#define S_T 0
#define S_MAXT 1
#define S_DSTAR 2
#define S_NEED 3
#define S_TKEPT 4
#define S_U 5

// ---------------- single-dispatch decoupled-lookback exclusive scan ----------------
// desc[t] packs (value<<32 | status); status 0=invalid (pre-zeroed), 1=aggregate, 2=prefix.
// All grids here are <= 513 blocks (fully resident on 256 CUs), so lookback cannot deadlock.
__global__ void scan_lb(const u32* __restrict__ in, u32* __restrict__ out, int n,
                        u64* __restrict__ desc){
  __shared__ u32 sh[256];
  __shared__ u32 shPrefix;
  int tid=threadIdx.x, t=blockIdx.x;
  int base = t*LB_TILE + tid*8;
  u32 v[8]; u32 s=0;
#pragma unroll
  for(int k=0;k<8;k++){ u32 xv=(base+k<n)?in[base+k]:0u; v[k]=s; s+=xv; }
  sh[tid]=s; __syncthreads();
  for(int o=1;o<256;o<<=1){
    u32 y=(tid>=o)?sh[tid-o]:0u;
    __syncthreads();
    sh[tid]+=y;
    __syncthreads();
  }
  u32 tileEx = (tid==0)?0u:sh[tid-1];
  u32 agg = sh[255];
  if(tid==0){
    u32 prefix=0u;
    if(t==0){
      atomicExch(&desc[0], ((u64)agg<<32)|2ull);
    } else {
      atomicExch(&desc[t], ((u64)agg<<32)|1ull);
      int j=t-1;
      while(true){
        u64 d=atomicAdd(&desc[j],0ull);   // coherent device-scope read
        u32 st=(u32)d;
        if(st==0u) continue;
        prefix += (u32)(d>>32);
        if(st==2u) break;
        --j;
      }
      atomicExch(&desc[t], ((u64)(prefix+agg)<<32)|2ull);
    }
    shPrefix=prefix;
  }
  __syncthreads();
  u32 p=shPrefix+tileEx;
#pragma unroll
  for(int k=0;k<8;k++){ if(base+k<n) out[base+k]=p+v[k]; }
}

// ---------------- stable 8-bit radix pass ----------------
__global__ void rx_hist(const u32* __restrict__ keys, u32* __restrict__ hist,
                        int B, int shift, int hostN, const int* __restrict__ dN){
  __shared__ u32 h[256];
  int n = (hostN>=0) ? hostN : dN[S_T];
  h[threadIdx.x]=0u; __syncthreads();
  int base = blockIdx.x*RX_CHUNK;
  for(int k=threadIdx.x;k<RX_CHUNK;k+=256){
    int p = base+k;
    if(p<n){ u32 d=(keys[p]>>shift)&255u; atomicAdd(&h[d],1u); }
  }
  __syncthreads();
  hist[threadIdx.x*B + blockIdx.x] = h[threadIdx.x]; // digit-major layout
}

// one wave per block; processes its chunk in index order -> stable
__global__ void rx_scatter(const u32* __restrict__ keys, const u32* __restrict__ pays,
                           u32* __restrict__ okeys, u32* __restrict__ opays,
                           const u32* __restrict__ basep, int B, int shift,
                           int hostN, const int* __restrict__ dN){
  __shared__ u32 cnt[256];
  int n = (hostN>=0) ? hostN : dN[S_T];
  int lane = threadIdx.x;
  for(int i=lane;i<256;i+=64) cnt[i]=0u;
  __syncthreads();
  int start = blockIdx.x*RX_CHUNK;
  for(int it=0; it<RX_CHUNK/64; ++it){
    int p = start + it*64 + lane;
    bool act = (p<n);
    u32 key = act ? keys[p] : 0u;
    u32 pay = act ? (pays ? pays[p] : (u32)p) : 0u;
    u32 dig = (key>>shift)&255u;
    u64 m = __ballot(act ? 1 : 0);
    for(int bb=0;bb<8;bb++){
      u64 bl = __ballot((int)((dig>>bb)&1u));
      m &= ((dig>>bb)&1u) ? bl : ~bl;
    }
    u64 lt = (1ull<<lane) - 1ull;
    u32 rb = (u32)__popcll(m & lt);
    u32 c = cnt[dig];
    if(act && rb==0u) atomicAdd(&cnt[dig], (u32)__popcll(m));
    __syncthreads();
    if(act){
      u32 pos = basep[dig*B + blockIdx.x] + c + rb;
      okeys[pos]=key; opays[pos]=pay;
    }
  }
}

// ---------------- pipeline kernels ----------------
__global__ void k_gather_edges(const u32* __restrict__ skeys, const u32* __restrict__ sperm,
                               const u32* __restrict__ tgt, u32* s0, u32* t0, int E){
  int j = blockIdx.x*256+threadIdx.x;
  if(j<E){ s0[j]=skeys[j]; t0[j]=tgt[sperm[j]]; }
}

__global__ void k_hist_vals(const u32* __restrict__ vals, u32* cnt, int n){
  int i=blockIdx.x*256+threadIdx.x;
  if(i<n) atomicAdd(&cnt[vals[i]],1u);
}

// deg decomposition over edges: tri0 adds cntS[tgt] at src; tri2 adds cntT[src] at tgt
__global__ void k_deg2(const u32* __restrict__ src, const u32* __restrict__ tgt,
                       const u32* __restrict__ cntS, const u32* __restrict__ cntT,
                       u32* deg, int E){
  int e=blockIdx.x*256+threadIdx.x;
  if(e>=E) return;
  u32 s=src[e], t=tgt[e];
  u32 w0=cntS[t]; if(w0) atomicAdd(&deg[s], w0);
  u32 w2=cntT[s]; if(w2) atomicAdd(&deg[t], w2);
}

// tri1 closed form + finalize deg + maxTri
__global__ void k_degNode(const u32* __restrict__ cntS, const u32* __restrict__ cntT,
                          u32* deg, int NN, int* scal){
  int v=blockIdx.x*256+threadIdx.x;
  if(v>=NN) return;
  u32 d = deg[v] + cntS[v]*cntT[v];
  deg[v]=d;
  if(d) atomicMax(&scal[S_MAXT], v);
}

__global__ void k_calc_cnts(const u32* __restrict__ s0, const u32* __restrict__ rp_tgt,
                            u32* cnts, int E){
  int e=blockIdx.x*256+threadIdx.x;
  if(e>E) return;
  if(e==E){ cnts[e]=0u; return; }
  u32 s=s0[e];
  cnts[e]=rp_tgt[s+1]-rp_tgt[s];
}

__global__ void k_set_T(const u32* __restrict__ start, int E, int* scal){
  int t=(int)start[E];
  scal[S_T]= (t<TCAP) ? t : TCAP;
}

__global__ void k_gen_tri(const u32* __restrict__ s0, const u32* __restrict__ t0,
                          const u32* __restrict__ ordT, const u32* __restrict__ rp_tgt,
                          const u32* __restrict__ cnts, const u32* __restrict__ start,
                          u32* tri0, u32* tri1, u32* tri2, int E){
  int e=blockIdx.x*256+threadIdx.x;
  if(e>=E) return;
  u32 s=s0[e], te=t0[e];
  u32 lb=rp_tgt[s], c=cnts[e], st=start[e];
  for(u32 i=0;i<c;i++){
    u32 idx=st+i; if(idx>=TCAP) break;
    u32 h=ordT[lb+i];
    tri0[idx]=s0[h]; tri1[idx]=t0[h]; tri2[idx]=te;
  }
}

__global__ void k_gather_tri(const u32* __restrict__ skeys, const u32* __restrict__ sperm,
                             const u32* __restrict__ t1g, const u32* __restrict__ t2g,
                             u32* t0s, u32* t1s, u32* t2s, const int* __restrict__ scal){
  int p=blockIdx.x*256+threadIdx.x;
  if(p>=scal[S_T]) return;
  u32 pp=sperm[p];
  t0s[p]=skeys[p]; t1s[p]=t1g[pp]; t2s[p]=t2g[pp];
}

__global__ void k_degHist(const u32* __restrict__ deg, u32* dh, int NN, const int* __restrict__ scal){
  int v=blockIdx.x*256+threadIdx.x;
  if(v>=NN || v>scal[S_MAXT]) return;
  u32 d=deg[v]; if(d>65535u)d=65535u;
  atomicAdd(&dh[d],1u);
}

__global__ void k_find_dstar(const u32* __restrict__ dh, const u32* __restrict__ dhs, int* scal){
  int d=blockIdx.x*256+threadIdx.x;
  if(d>=65536) return;
  long long kk=(((long long)scal[S_MAXT])+1)>>1;
  if(kk==0){ if(d==0){ scal[S_DSTAR]=-1; scal[S_NEED]=0; } return; }
  long long cum=(long long)dhs[d], h=(long long)dh[d];
  if(cum<=kk-1 && kk-1<cum+h){ scal[S_DSTAR]=d; scal[S_NEED]=(int)(kk-cum); }
}

__global__ void k_ef(const u32* __restrict__ deg, u32* ef, int NN, const int* __restrict__ scal){
  int v=blockIdx.x*256+threadIdx.x;
  if(v>NN) return;
  ef[v] = (v<NN && (int)deg[v]==scal[S_DSTAR]) ? 1u:0u;
}

__global__ void k_keep(const u32* __restrict__ deg, const u32* __restrict__ rankEq,
                       u32* keep, int NN, const int* __restrict__ scal){
  int v=blockIdx.x*256+threadIdx.x;
  if(v>=NN) return;
  int d=(int)deg[v]; int ds=scal[S_DSTAR]; int need=scal[S_NEED];
  u32 kp=1u;
  if(d<ds) kp=0u;
  else if(d==ds && (int)rankEq[v]<need) kp=0u;
  keep[v]=kp;
}

__global__ void k_mask(const u32* __restrict__ t0s, const u32* __restrict__ t1s,
                       const u32* __restrict__ t2s, const u32* __restrict__ keep,
                       u32* mask, const int* __restrict__ scal){
  int p=blockIdx.x*256+threadIdx.x;
  if(p>TCAP) return;
  u32 m=0u;
  if(p<scal[S_T]) m = keep[t0s[p]] & keep[t1s[p]] & keep[t2s[p]];
  mask[p]=m;
}

__global__ void k_set_tkept(const u32* __restrict__ msPos, int* scal){
  scal[S_TKEPT]=(int)msPos[scal[S_T]];
}

__global__ void k_compact(const u32* __restrict__ t0s, const u32* __restrict__ t1s,
                          const u32* __restrict__ t2s, const u32* __restrict__ mask,
                          const u32* __restrict__ msPos, u32* ks,u32* km,u32* kt,
                          const int* __restrict__ scal){
  int p=blockIdx.x*256+threadIdx.x;
  if(p>=scal[S_T] || !mask[p]) return;
  u32 q=msPos[p];
  ks[q]=t0s[p]; km[q]=t1s[p]; kt[q]=t2s[p];
}

__global__ void k_heads(const u32* __restrict__ ks, u32* hf, const int* __restrict__ scal){
  int q=blockIdx.x*256+threadIdx.x;
  if(q>TCAP) return;
  u32 f=0u;
  int Tk=scal[S_TKEPT];
  if(q<Tk) f = (q==0 || ks[q]!=ks[q-1]) ? 1u:0u;
  hf[q]=f;
}

__global__ void k_set_U(const u32* __restrict__ hs, u32* gs, int* scal){
  int Tk=scal[S_TKEPT];
  int U=(int)hs[Tk];
  scal[S_U]=U;
  gs[U]=(u32)Tk;
}

__global__ void k_gs(const u32* __restrict__ hf, const u32* __restrict__ hs,
                     u32* gs, const int* __restrict__ scal){
  int q=blockIdx.x*256+threadIdx.x;
  if(q>=scal[S_TKEPT]) return;
  if(hf[q]) gs[hs[q+1]-1u]=(u32)q;
}

__global__ void k_present(const u32* __restrict__ ks,const u32* __restrict__ km,
                          const u32* __restrict__ kt, u32* present, const int* __restrict__ scal){
  int q=blockIdx.x*256+threadIdx.x;
  if(q>=scal[S_TKEPT]) return;
  present[ks[q]]=1u; present[km[q]]=1u; present[kt[q]]=1u;
}

__global__ void k_write_ei(const u32* __restrict__ ks,const u32* __restrict__ km,
                           const u32* __restrict__ kt, const u32* __restrict__ newid,
                           float* out, const int* __restrict__ scal, int out_size){
  int q=blockIdx.x*256+threadIdx.x;
  int Tk=scal[S_TKEPT];
  if(q>=Tk) return;
  int bs=scal[S_U]*64;
  int i0=bs+q, i1=bs+Tk+q, i2=bs+2*Tk+q;
  if(i0<out_size) out[i0]=(float)newid[ks[q]];
  if(i1<out_size) out[i1]=(float)newid[km[q]];
  if(i2<out_size) out[i2]=(float)newid[kt[q]];
}

// x_new: per group g (one wave), a0 = cnt*x[uniq] (ks constant in group!), gather only km/kt.
// W cached in LDS once per block, transposed with stride 65 (conflict-free both ways).
__global__ __launch_bounds__(256) void k_xnew2(const float* __restrict__ x,
    const float* __restrict__ W, const float* __restrict__ b,
    const u32* __restrict__ ks, const u32* __restrict__ km, const u32* __restrict__ kt,
    const u32* __restrict__ gs, float* __restrict__ out,
    const int* __restrict__ scal){
  __shared__ float Wl[192*65];
  __shared__ float sv[4][192];
  int tid=threadIdx.x;
  for(int j=tid;j<12288;j+=256){
    int r=j%192, o=j/192;      // j = (o*64+i)*3+k ; r = i*3+k
    Wl[r*65+o]=W[j];
  }
  __syncthreads();
  int U=scal[S_U];
  int w=tid>>6, lane=tid&63;
  float bv=b[lane];
  for(int g=blockIdx.x*4+w; g<U; g+=gridDim.x*4){
    u32 q0=gs[g], q1=gs[g+1];
    float a1=0.f,a2=0.f;
    for(u32 q=q0;q<q1;q++){
      u32 rm=km[q], rt=kt[q];
      a1 += x[(size_t)rm*64+lane];
      a2 += x[(size_t)rt*64+lane];
    }
    float xu = x[(size_t)ks[q0]*64+lane];
    sv[w][lane]=xu; sv[w][64+lane]=a1; sv[w][128+lane]=a2;
    __builtin_amdgcn_s_waitcnt(0); // drain lgkm before same-wave LDS read
    float acc0=0.f, acc12=0.f;
#pragma unroll 4
    for(int ii=0;ii<64;ii++){
      float x0=sv[w][ii], x1=sv[w][64+ii], x2=sv[w][128+ii];
      acc0  += Wl[(ii*3+0)*65+lane]*x0;
      acc12 += Wl[(ii*3+1)*65+lane]*x1 + Wl[(ii*3+2)*65+lane]*x2;
    }
    float invc = 1.f/(float)(q1-q0);
    out[(size_t)g*64+lane] = bv + acc0 + acc12*invc;
  }
}

extern "C" void kernel_launch(void* const* d_in, const int* in_sizes, int n_in,
                              void* d_out, int out_size, void* d_ws, size_t ws_size,
                              hipStream_t stream){
  const float* x = (const float*)d_in[0];
  const int*   ei = (const int*)d_in[1];
  const float* W = (const float*)d_in[2];
  const float* b = (const float*)d_in[3];
  int NN = in_sizes[0]/64;
  int E  = in_sizes[1]/2;
  const u32* src=(const u32*)ei;
  const u32* tgt=(const u32*)(ei+E);

  // bump allocator over d_ws (256B aligned)
  char* base=(char*)d_ws; size_t off=0;
  auto alloc=[&](size_t nInts)->u32*{
    u32* p=(u32*)(base+off);
    off += ( (nInts*4 + 255) & ~(size_t)255 );
    return p;
  };
  // ---- zero-zone (one memset): scal, histograms, deg, present, lookback descriptors ----
  int* scal=(int*)alloc(64);
  u32* cntNode=alloc(NN+1); u32* cntSrc=alloc(NN);
  u32* deg=alloc(NN); u32* degHist=alloc(65536);
  u32* present=alloc(NN+1);
  u64* desc=(u64*)alloc(8192);          // 4096 u64 descriptors
  size_t zoneBytes = off;
  // ---- rest ----
  u32* keyA=alloc(TCAP+1); u32* payA=alloc(TCAP+1);
  u32* keyB=alloc(TCAP+1); u32* payB=alloc(TCAP+1);
  u32* s0=alloc(E); u32* t0=alloc(E);
  u32* rp_tgt=alloc(NN+1);
  u32* cnts=alloc(E+1); u32* start=alloc(E+1);
  u32* tri0g=alloc(TCAP); u32* tri1g=alloc(TCAP); u32* tri2g=alloc(TCAP);
  u32* tri0s=alloc(TCAP); u32* tri1s=alloc(TCAP); u32* tri2s=alloc(TCAP);
  u32* degHistScan=alloc(65536);
  u32* ef=alloc(NN+1); u32* rankEq=alloc(NN+1); u32* keep=alloc(NN);
  u32* newid=alloc(NN+1); u32* gs=alloc(NN+2);
  u32* rxhist=alloc(256*(TCAP/RX_CHUNK));
  if(off > ws_size) return;

  // aliases (live ranges verified disjoint)
  u32* mask=keyB; u32* msPos=payB; u32* hf=keyA; u32* hs=payA;
  u32* ks=tri0g; u32* km=tri1g; u32* kt=tri2g;

  size_t descUsed=0;
  auto scan_ex=[&](const u32* in, u32* out, int n){
    int nb=(n+LB_TILE-1)/LB_TILE;
    scan_lb<<<nb,256,0,stream>>>(in,out,n,desc+descUsed);
    descUsed += (size_t)nb;
  };
  auto rx_pass=[&](const u32* kin,const u32* pin,u32* kout,u32* pout,
                   int B,int shift,int hostN){
    rx_hist<<<B,256,0,stream>>>(kin,rxhist,B,shift,hostN,scal);
    scan_ex(rxhist,rxhist,256*B);
    rx_scatter<<<B,64,0,stream>>>(kin,pin,kout,pout,rxhist,B,shift,hostN,scal);
  };

  int gE=(E+255)/256, gE1=(E+256)/256;
  int gNN=(NN+255)/256, gNN1=(NN+256)/256;
  int gTC=(TCAP+255)/256, gTC1=(TCAP+256)/256;
  int BE=(E+RX_CHUNK-1)/RX_CHUNK;
  int BT=TCAP/RX_CHUNK;

  hipMemsetAsync(base,0,zoneBytes,stream);

  // --- degree-prune inputs computable straight from edges (no triplets needed) ---
  k_hist_vals<<<gE,256,0,stream>>>(tgt,cntNode,E);
  k_hist_vals<<<gE,256,0,stream>>>(src,cntSrc,E);
  k_deg2<<<gE,256,0,stream>>>(src,tgt,cntSrc,cntNode,deg,E);
  k_degNode<<<gNN,256,0,stream>>>(cntSrc,cntNode,deg,NN,scal);
  k_degHist<<<gNN,256,0,stream>>>(deg,degHist,NN,scal);
  scan_ex(degHist,degHistScan,65536);
  k_find_dstar<<<256,256,0,stream>>>(degHist,degHistScan,scal);
  k_ef<<<gNN1,256,0,stream>>>(deg,ef,NN,scal);
  scan_ex(ef,rankEq,NN+1);
  k_keep<<<gNN,256,0,stream>>>(deg,rankEq,keep,NN,scal);

  // --- rp_tgt CSR (== searchsorted lb/ub) ---
  scan_ex(cntNode,rp_tgt,NN+1);

  // --- sort 1: stable sort edges by src ---
  rx_pass(src,nullptr,keyB,payB,BE,0,E);
  rx_pass(keyB,payB,keyA,payA,BE,8,E);
  k_gather_edges<<<gE,256,0,stream>>>(keyA,payA,tgt,s0,t0,E);

  // --- sort 2: stable argsort of t0 -> ordT (payA) ---
  rx_pass(t0,nullptr,keyB,payB,BE,0,E);
  rx_pass(keyB,payB,keyA,payA,BE,8,E);

  // --- counts / start / T ---
  k_calc_cnts<<<gE1,256,0,stream>>>(s0,rp_tgt,cnts,E);
  scan_ex(cnts,start,E+1);
  k_set_T<<<1,1,0,stream>>>(start,E,scal);

  // --- generate triplets (natural (e,i) order) ---
  k_gen_tri<<<gE,256,0,stream>>>(s0,t0,payA,rp_tgt,cnts,start,tri0g,tri1g,tri2g,E);

  // --- sort 3: stable sort triplets by tri[0] ---
  rx_pass(tri0g,nullptr,keyB,payB,BT,0,-1);
  rx_pass(keyB,payB,keyA,payA,BT,8,-1);
  k_gather_tri<<<gTC,256,0,stream>>>(keyA,payA,tri1g,tri2g,tri0s,tri1s,tri2s,scal);

  // --- mask + compact kept triplets (order preserved) ---
  k_mask<<<gTC1,256,0,stream>>>(tri0s,tri1s,tri2s,keep,mask,scal);
  scan_ex(mask,msPos,TCAP+1);
  k_set_tkept<<<1,1,0,stream>>>(msPos,scal);
  k_compact<<<gTC,256,0,stream>>>(tri0s,tri1s,tri2s,mask,msPos,ks,km,kt,scal);

  // --- group boundaries over kept srcs ---
  k_heads<<<gTC1,256,0,stream>>>(ks,hf,scal);
  scan_ex(hf,hs,TCAP+1);
  k_set_U<<<1,1,0,stream>>>(hs,gs,scal);
  k_gs<<<gTC,256,0,stream>>>(hf,hs,gs,scal);

  // --- newid = rank among distinct node values in tri_kept ---
  k_present<<<gTC,256,0,stream>>>(ks,km,kt,present,scal);
  scan_ex(present,newid,NN+1);

  // --- outputs ---
  float* outF=(float*)d_out;
  k_write_ei<<<gTC,256,0,stream>>>(ks,km,kt,newid,outF,scal,out_size);
  k_xnew2<<<512,256,0,stream>>>(x,W,b,ks,km,kt,gs,outF,scal);
}

// Round 5
// 375.547 us; speedup vs baseline: 2.0674x; 1.2018x over previous
//
#include <hip/hip_runtime.h>
#include <stdint.h>

typedef uint32_t u32;
typedef unsigned long long u64;

#define LB_TILE 2048

// scal[] slots
#define S_MAXT 1
#define S_DSTAR 2
#define S_NEED 3
#define S_U 5

// ---------------- single-dispatch decoupled-lookback exclusive scan ----------------
// desc[t] packs (value<<32 | status); 0=invalid (pre-zeroed), 1=aggregate, 2=prefix.
// All scan grids here are <=~230 blocks (fully resident on 256 CUs) -> no deadlock.
__global__ void scan_lb(const u32* __restrict__ in, u32* __restrict__ out, int n,
                        u64* __restrict__ desc){
  __shared__ u32 sh[256];
  __shared__ u32 shPrefix;
  int tid=threadIdx.x, t=blockIdx.x;
  int base = t*LB_TILE + tid*8;
  u32 v[8]; u32 s=0;
#pragma unroll
  for(int k=0;k<8;k++){ u32 xv=(base+k<n)?in[base+k]:0u; v[k]=s; s+=xv; }
  sh[tid]=s; __syncthreads();
  for(int o=1;o<256;o<<=1){
    u32 y=(tid>=o)?sh[tid-o]:0u;
    __syncthreads();
    sh[tid]+=y;
    __syncthreads();
  }
  u32 tileEx = (tid==0)?0u:sh[tid-1];
  u32 agg = sh[255];
  if(tid==0){
    u32 prefix=0u;
    if(t==0){
      atomicExch(&desc[0], ((u64)agg<<32)|2ull);
    } else {
      atomicExch(&desc[t], ((u64)agg<<32)|1ull);
      int j=t-1;
      while(true){
        u64 d=atomicAdd(&desc[j],0ull);
        u32 st=(u32)d;
        if(st==0u) continue;
        prefix += (u32)(d>>32);
        if(st==2u) break;
        --j;
      }
      atomicExch(&desc[t], ((u64)(prefix+agg)<<32)|2ull);
    }
    shPrefix=prefix;
  }
  __syncthreads();
  u32 p=shPrefix+tileEx;
#pragma unroll
  for(int k=0;k<8;k++){ if(base+k<n) out[base+k]=p+v[k]; }
}

// ---------------- stable 8-bit radix pass on packed u64 ----------------
__global__ void rx_hist64(const u64* __restrict__ keys, u32* __restrict__ hist,
                          int B, int shift, int chunk, int hostN,
                          const u32* __restrict__ dCount, int cap){
  __shared__ u32 h[256];
  int n = (hostN>=0) ? hostN : (int)(*dCount<(u32)cap?*dCount:(u32)cap);
  h[threadIdx.x]=0u; __syncthreads();
  int base = blockIdx.x*chunk;
  for(int k=threadIdx.x;k<chunk;k+=256){
    int p = base+k;
    if(p<n){ u32 d=(u32)(keys[p]>>shift)&255u; atomicAdd(&h[d],1u); }
  }
  __syncthreads();
  hist[threadIdx.x*B + blockIdx.x] = h[threadIdx.x]; // digit-major
}

// one wave per block; processes chunk in index order -> stable
__global__ void rx_scatter64(const u64* __restrict__ keys, u64* __restrict__ okeys,
                             const u32* __restrict__ basep, int B, int shift, int chunk,
                             int hostN, const u32* __restrict__ dCount, int cap){
  __shared__ u32 cnt[256];
  int n = (hostN>=0) ? hostN : (int)(*dCount<(u32)cap?*dCount:(u32)cap);
  int lane = threadIdx.x;
  for(int i=lane;i<256;i+=64) cnt[i]=0u;
  __syncthreads();
  int start = blockIdx.x*chunk;
  int rounds = chunk>>6;
  for(int it=0; it<rounds; ++it){
    int p = start + it*64 + lane;
    bool act = (p<n);
    u64 key = act ? keys[p] : 0ull;
    u32 dig = (u32)(key>>shift)&255u;
    u64 m = __ballot(act ? 1 : 0);
    for(int bb=0;bb<8;bb++){
      u64 bl = __ballot((int)((dig>>bb)&1u));
      m &= ((dig>>bb)&1u) ? bl : ~bl;
    }
    u64 lt = (1ull<<lane) - 1ull;
    u32 rb = (u32)__popcll(m & lt);
    u32 c = cnt[dig];
    if(act && rb==0u) atomicAdd(&cnt[dig], (u32)__popcll(m));
    __syncthreads();
    if(act) okeys[basep[dig*B + blockIdx.x] + c + rb] = key;
  }
}

// ---------------- pipeline kernels ----------------
__global__ void k_hist2(const u32* __restrict__ src, const u32* __restrict__ tgt,
                        u32* cntS, u32* cntT, int E){
  int j=blockIdx.x*256+threadIdx.x;
  if(j<E){ atomicAdd(&cntS[src[j]],1u); atomicAdd(&cntT[tgt[j]],1u); }
}

// deg closed form over edges: tri0 adds cntS[tgt] at src; tri2 adds cntT[src] at tgt
__global__ void k_deg2(const u32* __restrict__ src, const u32* __restrict__ tgt,
                       const u32* __restrict__ cntS, const u32* __restrict__ cntT,
                       u32* deg, int E){
  int e=blockIdx.x*256+threadIdx.x;
  if(e>=E) return;
  u32 s=src[e], t=tgt[e];
  u32 w0=cntS[t]; if(w0) atomicAdd(&deg[s], w0);
  u32 w2=cntT[s]; if(w2) atomicAdd(&deg[t], w2);
}

// tri1 closed form + finalize deg + maxTri
__global__ void k_degNode(const u32* __restrict__ cntS, const u32* __restrict__ cntT,
                          u32* deg, int NN, int* scal){
  int v=blockIdx.x*256+threadIdx.x;
  if(v>=NN) return;
  u32 d = deg[v] + cntS[v]*cntT[v];
  deg[v]=d;
  if(d) atomicMax(&scal[S_MAXT], v);
}

__global__ void k_degHist(const u32* __restrict__ deg, u32* dh, int NN, const int* __restrict__ scal){
  int v=blockIdx.x*256+threadIdx.x;
  if(v>=NN || v>scal[S_MAXT]) return;
  u32 d=deg[v]; if(d>65535u)d=65535u;
  atomicAdd(&dh[d],1u);
}

__global__ void k_find_dstar(const u32* __restrict__ dh, const u32* __restrict__ dhs, int* scal){
  int d=blockIdx.x*256+threadIdx.x;
  if(d>=65536) return;
  long long kk=(((long long)scal[S_MAXT])+1)>>1;
  if(kk==0){ if(d==0){ scal[S_DSTAR]=-1; scal[S_NEED]=0; } return; }
  long long cum=(long long)dhs[d], h=(long long)dh[d];
  if(cum<=kk-1 && kk-1<cum+h){ scal[S_DSTAR]=d; scal[S_NEED]=(int)(kk-cum); }
}

__global__ void k_ef(const u32* __restrict__ deg, u32* ef, int NN, const int* __restrict__ scal){
  int v=blockIdx.x*256+threadIdx.x;
  if(v>NN) return;
  ef[v] = (v<NN && v<=scal[S_MAXT] && (int)deg[v]==scal[S_DSTAR]) ? 1u:0u;
}

__global__ void k_keep(const u32* __restrict__ deg, const u32* __restrict__ rankEq,
                       u32* keep, int NN, const int* __restrict__ scal){
  int v=blockIdx.x*256+threadIdx.x;
  if(v>=NN) return;
  int d=(int)deg[v]; int ds=scal[S_DSTAR]; int need=scal[S_NEED];
  u32 kp=1u;
  if(d<ds) kp=0u;
  else if(d==ds && (int)rankEq[v]<need) kp=0u;
  keep[v]=kp;
}

// keptCnt[u] = #{h: tgt[h]=u && keep[src[h]]}
__global__ void k_keptCnt(const u32* __restrict__ src, const u32* __restrict__ tgt,
                          const u32* __restrict__ keep, u32* kc, int E){
  int j=blockIdx.x*256+threadIdx.x;
  if(j<E && keep[src[j]]) atomicAdd(&kc[tgt[j]],1u);
}

__global__ void k_mk_ek(const u32* __restrict__ src, const u32* __restrict__ tgt,
                        u64* ek, int E){
  int j=blockIdx.x*256+threadIdx.x;
  if(j<E) ek[j]=((u64)src[j]<<20)|(u64)tgt[j];
}

__global__ void k_mk_a2(const u64* __restrict__ eks, u64* a2, int E){
  int j=blockIdx.x*256+threadIdx.x;
  if(j<E) a2[j]=((eks[j]&0xFFFFFull)<<20)|(u64)j;
}

// kept triplet count per rep edge, O(1)
__global__ void k_cntk(const u64* __restrict__ eks, const u32* __restrict__ keep,
                       const u32* __restrict__ keptCnt, u32* cntk, int E){
  int e=blockIdx.x*256+threadIdx.x;
  if(e>E) return;
  if(e==E){ cntk[e]=0u; return; }
  u64 ke=eks[e];
  u32 s=(u32)(ke>>20), te=(u32)(ke&0xFFFFFull);
  cntk[e] = (keep[s]&keep[te]) ? keptCnt[s] : 0u;
}

// generate ONLY kept triplets, pre-compacted, in (e,i)-order; packed hs<<30|s<<15|te
__global__ void k_gen_trik(const u64* __restrict__ eks, const u64* __restrict__ a2s,
                           const u32* __restrict__ rp_tgt, const u32* __restrict__ keep,
                           const u32* __restrict__ startk, u64* __restrict__ trig,
                           int E, int cap){
  int e=blockIdx.x*256+threadIdx.x;
  if(e>=E) return;
  u32 c0=startk[e], c1=startk[e+1];
  if(c0>=c1) return;
  u64 ke=eks[e];
  u32 s=(u32)(ke>>20), te=(u32)(ke&0xFFFFFull);
  u32 lb=rp_tgt[s], ub=rp_tgt[s+1];
  u32 idx=c0;
  for(u32 i=lb; i<ub && idx<c1; ++i){
    u32 h=(u32)(a2s[i]&0xFFFFFull);
    u32 hs=(u32)(eks[h]>>20);
    if(keep[hs]){
      if(idx<(u32)cap) trig[idx]=((u64)hs<<30)|((u64)s<<15)|(u64)te;
      ++idx;
    }
  }
}

__global__ void k_heads_present(const u64* __restrict__ tri, u32* hf, u32* present,
                                const u32* __restrict__ dCount, int cap){
  int Tk=(int)(*dCount<(u32)cap?*dCount:(u32)cap);
  int q=blockIdx.x*256+threadIdx.x;
  if(q>cap) return;
  u32 f=0u;
  if(q<Tk){
    u64 key=tri[q];
    f = (q==0 || (key>>30)!=(tri[q-1]>>30)) ? 1u:0u;
    present[key>>30]=1u; present[(key>>15)&0x7FFFu]=1u; present[key&0x7FFFu]=1u;
  }
  hf[q]=f;
}

__global__ void k_gs2(const u32* __restrict__ hf, const u32* __restrict__ hs,
                      u32* gs, int* scal, const u32* __restrict__ dCount, int cap){
  int Tk=(int)(*dCount<(u32)cap?*dCount:(u32)cap);
  int q=blockIdx.x*256+threadIdx.x;
  if(q==0){ int U=(int)hs[Tk]; scal[S_U]=U; gs[U]=(u32)Tk; }
  if(q>=Tk) return;
  if(hf[q]) gs[hs[q+1]-1u]=(u32)q;
}

__global__ void k_write_ei(const u64* __restrict__ tri, const u32* __restrict__ newid,
                           float* out, const int* __restrict__ scal,
                           const u32* __restrict__ dCount, int cap, int out_size){
  int Tk=(int)(*dCount<(u32)cap?*dCount:(u32)cap);
  int q=blockIdx.x*256+threadIdx.x;
  if(q>=Tk) return;
  u64 key=tri[q];
  int bs=scal[S_U]*64;
  int i0=bs+q, i1=bs+Tk+q, i2=bs+2*Tk+q;
  if(i0<out_size) out[i0]=(float)newid[key>>30];
  if(i1<out_size) out[i1]=(float)newid[(key>>15)&0x7FFFu];
  if(i2<out_size) out[i2]=(float)newid[key&0x7FFFu];
}

// x_new: one wave per group; a0 = x[uniq] (count cancels), gather km/kt rows from tri64.
// W cached in LDS stride-65 (conflict-free for staging writes AND inner reads).
__global__ __launch_bounds__(256) void k_xnew3(const float* __restrict__ x,
    const float* __restrict__ W, const float* __restrict__ b,
    const u64* __restrict__ tri, const u32* __restrict__ gs,
    float* __restrict__ out, const int* __restrict__ scal){
  __shared__ float Wl[192*65];
  __shared__ float sv[4][192];
  int tid=threadIdx.x;
  for(int j=tid;j<12288;j+=256){
    int r=j%192, o=j/192;      // j=(o*64+i)*3+k ; r=i*3+k
    Wl[r*65+o]=W[j];
  }
  __syncthreads();
  int U=scal[S_U];
  int w=tid>>6, lane=tid&63;
  float bv=b[lane];
  for(int g=blockIdx.x*4+w; g<U; g+=gridDim.x*4){
    u32 q0=gs[g], q1=gs[g+1];
    float a1=0.f,a2=0.f;
    for(u32 q=q0;q<q1;q++){
      u64 key=tri[q];
      a1 += x[(size_t)((key>>15)&0x7FFFull)*64+lane];
      a2 += x[(size_t)(key&0x7FFFull)*64+lane];
    }
    float xu = x[(size_t)(tri[q0]>>30)*64+lane];
    sv[w][lane]=xu; sv[w][64+lane]=a1; sv[w][128+lane]=a2;
    float acc0=0.f, acc12=0.f;
#pragma unroll 4
    for(int ii=0;ii<64;ii++){
      acc0  += Wl[(ii*3+0)*65+lane]*sv[w][ii];
      acc12 += Wl[(ii*3+1)*65+lane]*sv[w][64+ii]
             + Wl[(ii*3+2)*65+lane]*sv[w][128+ii];
    }
    out[(size_t)g*64+lane] = bv + acc0 + acc12/(float)(q1-q0);
  }
}

extern "C" void kernel_launch(void* const* d_in, const int* in_sizes, int n_in,
                              void* d_out, int out_size, void* d_ws, size_t ws_size,
                              hipStream_t stream){
  const float* x = (const float*)d_in[0];
  const int*   ei = (const int*)d_in[1];
  const float* W = (const float*)d_in[2];
  const float* b = (const float*)d_in[3];
  int NN = in_sizes[0]/64;
  int E  = in_sizes[1]/2;
  const u32* src=(const u32*)ei;
  const u32* tgt=(const u32*)(ei+E);

  // Tk <= out_size/3 exactly (out_size = 64U + 3Tk); round capacity to chunk multiple
  int KCAP = ((out_size/3 + 1023)/1024)*1024; if(KCAP<1024) KCAP=1024;

  char* base=(char*)d_ws; size_t off=0;
  auto alloc=[&](size_t nInts)->u32*{
    u32* p=(u32*)(base+off);
    off += ( (nInts*4 + 255) & ~(size_t)255 );
    return p;
  };
  // ---- zero-zone (one memset) ----
  int* scal=(int*)alloc(64);
  u32* cntT=alloc(NN+1); u32* cntS=alloc(NN);
  u32* deg=alloc(NN); u32* degHist=alloc(65536);
  u32* present=alloc(NN+1); u32* keptCnt=alloc(NN);
  u64* desc=(u64*)alloc(8192);          // 4096 u64 descriptors
  size_t zoneBytes = off;
  // ---- rest ----
  u64* ekA=(u64*)alloc(2*(size_t)E); u64* ekB=(u64*)alloc(2*(size_t)E);
  u64* a2A=(u64*)alloc(2*(size_t)E);
  u64* triA=(u64*)alloc(2*(size_t)KCAP); u64* triB=(u64*)alloc(2*(size_t)KCAP);
  u32* rp_tgt=alloc(NN+1);
  u32* cntk=alloc(E+1); u32* startk=alloc(E+1);
  u32* degHistScan=alloc(65536);
  u32* ef=alloc(NN+1); u32* rankEq=alloc(NN+1); u32* keep=alloc(NN);
  u32* newid=alloc(NN+1); u32* gs=alloc(NN+2);
  u32* hf=alloc(KCAP+1); u32* hs=alloc(KCAP+1);
  u32* rxhist=alloc(65536);
  if(off > ws_size) return;
  u64* a2B=ekB; // ekB dead after sort1

  size_t descUsed=0;
  auto scan_ex=[&](const u32* in, u32* out, int n){
    int nb=(n+LB_TILE-1)/LB_TILE;
    scan_lb<<<nb,256,0,stream>>>(in,out,n,desc+descUsed);
    descUsed += (size_t)nb;
  };
  auto rx_pass2=[&](const u64* kin, u64* kout, int B, int shift, int chunk,
                    int hostN, const u32* dCount, int cap){
    rx_hist64<<<B,256,0,stream>>>(kin,rxhist,B,shift,chunk,hostN,dCount,cap);
    scan_ex(rxhist,rxhist,256*B);
    rx_scatter64<<<B,64,0,stream>>>(kin,kout,rxhist,B,shift,chunk,hostN,dCount,cap);
  };

  int gE=(E+255)/256, gE1=(E+256)/256;
  int gNN=(NN+255)/256, gNN1=(NN+256)/256;
  int gKC=(KCAP+255)/256, gKC1=(KCAP+256)/256;
  int BE=(E+511)/512;
  int B3=KCAP/1024;

  hipMemsetAsync(base,0,zoneBytes,stream);

  // --- degree-prune chain straight from edges ---
  k_hist2<<<gE,256,0,stream>>>(src,tgt,cntS,cntT,E);
  k_deg2<<<gE,256,0,stream>>>(src,tgt,cntS,cntT,deg,E);
  k_degNode<<<gNN,256,0,stream>>>(cntS,cntT,deg,NN,scal);
  k_degHist<<<gNN,256,0,stream>>>(deg,degHist,NN,scal);
  scan_ex(degHist,degHistScan,65536);
  k_find_dstar<<<256,256,0,stream>>>(degHist,degHistScan,scal);
  k_ef<<<gNN1,256,0,stream>>>(deg,ef,NN,scal);
  scan_ex(ef,rankEq,NN+1);
  k_keep<<<gNN,256,0,stream>>>(deg,rankEq,keep,NN,scal);
  k_keptCnt<<<gE,256,0,stream>>>(src,tgt,keep,keptCnt,E);

  // --- rp_tgt CSR ---
  scan_ex(cntT,rp_tgt,NN+1);

  // --- sort 1: edges by src, packed src<<20|tgt (digits at 20,28) ---
  k_mk_ek<<<gE,256,0,stream>>>(src,tgt,ekA,E);
  rx_pass2(ekA,ekB,BE,20,512,E,nullptr,0);
  rx_pass2(ekB,ekA,BE,28,512,E,nullptr,0);   // eks = ekA

  // --- sort 2: argsort of t0, packed t0<<20|h (digits at 20,28) ---
  k_mk_a2<<<gE,256,0,stream>>>(ekA,a2A,E);
  rx_pass2(a2A,a2B,BE,20,512,E,nullptr,0);
  rx_pass2(a2B,a2A,BE,28,512,E,nullptr,0);   // ordT = a2A & 0xFFFFF

  // --- kept counts / offsets (O(1) per edge via keptCnt) ---
  k_cntk<<<gE1,256,0,stream>>>(ekA,keep,keptCnt,cntk,E);
  scan_ex(cntk,startk,E+1);

  // --- generate ONLY kept triplets, pre-compacted ---
  k_gen_trik<<<gE,256,0,stream>>>(ekA,a2A,rp_tgt,keep,startk,triA,E,KCAP);

  // --- sort 3: stable sort kept triplets by hs (digits at 30,38) ---
  rx_pass2(triA,triB,B3,30,1024,-1,startk+E,KCAP);
  rx_pass2(triB,triA,B3,38,1024,-1,startk+E,KCAP);

  // --- groups + presence + reindex ---
  k_heads_present<<<gKC1,256,0,stream>>>(triA,hf,present,startk+E,KCAP);
  scan_ex(hf,hs,KCAP+1);
  scan_ex(present,newid,NN+1);
  k_gs2<<<gKC,256,0,stream>>>(hf,hs,gs,scal,startk+E,KCAP);

  // --- outputs ---
  float* outF=(float*)d_out;
  k_write_ei<<<gKC,256,0,stream>>>(triA,newid,outF,scal,startk+E,KCAP,out_size);
  k_xnew3<<<768,256,0,stream>>>(x,W,b,triA,gs,outF,scal);
}

// Round 7
// 337.280 us; speedup vs baseline: 2.3020x; 1.1135x over previous
//
#include <hip/hip_runtime.h>
#include <stdint.h>

typedef uint32_t u32;
typedef unsigned long long u64;

#define LB_TILE 2048
#define OW_TILE 1024
#define RUN 32

// scal[] slots
#define S_MAXT 1
#define S_DSTAR 2
#define S_NEED 3
#define S_U 5

// ---------------- decoupled-lookback exclusive scan (1 dispatch) ----------------
__global__ void scan_lb(const u32* __restrict__ in, u32* __restrict__ out, int n,
                        u64* __restrict__ desc){
  __shared__ u32 sh[256];
  __shared__ u32 shPrefix;
  int tid=threadIdx.x, t=blockIdx.x;
  int base = t*LB_TILE + tid*8;
  u32 v[8]; u32 s=0;
#pragma unroll
  for(int k=0;k<8;k++){ u32 xv=(base+k<n)?in[base+k]:0u; v[k]=s; s+=xv; }
  sh[tid]=s; __syncthreads();
  for(int o=1;o<256;o<<=1){
    u32 y=(tid>=o)?sh[tid-o]:0u;
    __syncthreads();
    sh[tid]+=y;
    __syncthreads();
  }
  u32 tileEx = (tid==0)?0u:sh[tid-1];
  u32 agg = sh[255];
  if(tid==0){
    u32 prefix=0u;
    if(t==0){
      atomicExch(&desc[0], ((u64)agg<<32)|2ull);
    } else {
      atomicExch(&desc[t], ((u64)agg<<32)|1ull);
      int j=t-1;
      while(true){
        u64 d=atomicAdd(&desc[j],0ull);
        u32 st=(u32)d;
        if(st==0u) continue;
        prefix += (u32)(d>>32);
        if(st==2u) break;
        --j;
      }
      atomicExch(&desc[t], ((u64)(prefix+agg)<<32)|2ull);
    }
    shPrefix=prefix;
  }
  __syncthreads();
  u32 p=shPrefix+tileEx;
#pragma unroll
  for(int k=0;k<8;k++){ if(base+k<n) out[base+k]=p+v[k]; }
}

// ---------------- onesweep radix pass (1 dispatch; stable) ----------------
// gbase: global exclusive digit base (permutation-invariant, from pre-hist).
// desc[b*256+d]: per-digit lookback words, pre-zeroed. All blocks resident.
__global__ __launch_bounds__(256) void ow_pass(const u64* __restrict__ in,
    u64* __restrict__ outk, const u32* __restrict__ gbase, u64* __restrict__ desc,
    int shift, int hostN, const u32* __restrict__ dCount, int cap){
  __shared__ u32 hist[256], bd[256], cnt2[256];
  __shared__ u32 cnt4[4][256];
  int n = (hostN>=0)?hostN:(int)((*dCount)<(u32)cap?(*dCount):(u32)cap);
  int tid=threadIdx.x, b=blockIdx.x, w=tid>>6, lane=tid&63;
  int base=b*OW_TILE;
  hist[tid]=0u; cnt2[tid]=0u;
  cnt4[0][tid]=0u; cnt4[1][tid]=0u; cnt4[2][tid]=0u; cnt4[3][tid]=0u;
  __syncthreads();
  u64 k[4]; bool act[4];
#pragma unroll
  for(int i=0;i<4;i++){
    int p=base+i*256+tid; act[i]=(p<n);
    k[i]=act[i]?in[p]:0ull;
    if(act[i]) atomicAdd(&hist[(u32)(k[i]>>shift)&255u],1u);
  }
  __syncthreads();
  u32 agg=hist[tid];
  if(b==0){
    atomicExch(&desc[tid], ((u64)agg<<32)|2ull);
    bd[tid]=gbase[tid];
  } else {
    atomicExch(&desc[(size_t)b*256+tid], ((u64)agg<<32)|1ull);
    u32 pre=0u; int j=b-1;
    while(true){
      u64 d=atomicAdd(&desc[(size_t)j*256+tid],0ull);
      u32 st=(u32)d;
      if(st==0u) continue;
      pre+=(u32)(d>>32);
      if(st==2u) break;
      --j;
    }
    atomicExch(&desc[(size_t)b*256+tid], ((u64)(pre+agg)<<32)|2ull);
    bd[tid]=gbase[tid]+pre;
  }
  __syncthreads();
  // 4 superrounds, index order (sr,wave,lane) -> stable
#pragma unroll
  for(int i=0;i<4;i++){
    u32 dig=(u32)(k[i]>>shift)&255u;
    u64 m=__ballot(act[i]?1:0);
    for(int bb=0;bb<8;bb++){
      u64 bl=__ballot((int)((dig>>bb)&1u));
      m &= ((dig>>bb)&1u)?bl:~bl;
    }
    u32 rb=(u32)__popcll(m&((1ull<<lane)-1ull));
    if(act[i]&&rb==0u) cnt4[w][dig]=(u32)__popcll(m);
    __syncthreads();
    if(act[i]){
      u32 off=cnt2[dig]+rb;
      for(int w2=0;w2<w;w2++) off+=cnt4[w2][dig];
      outk[bd[dig]+off]=k[i];
    }
    __syncthreads();
    cnt2[tid]+=cnt4[0][tid]+cnt4[1][tid]+cnt4[2][tid]+cnt4[3][tid];
    cnt4[0][tid]=0u; cnt4[1][tid]=0u; cnt4[2][tid]=0u; cnt4[3][tid]=0u;
    __syncthreads();
  }
}

// pre-hist: all digit histograms of the initial array (perm-invariant)
__global__ void k_prehistE(const u64* __restrict__ keys, u32* __restrict__ hg, int n){
  __shared__ u32 h[4][256];
  int tid=threadIdx.x;
  for(int i=0;i<4;i++) h[i][tid]=0u;
  __syncthreads();
#pragma unroll
  for(int i=0;i<4;i++){
    int p=blockIdx.x*OW_TILE+i*256+tid;
    if(p<n){
      u64 key=keys[p];
      atomicAdd(&h[0][(u32)(key>>24)&255u],1u);
      atomicAdd(&h[1][(u32)(key>>32)&255u],1u);
      atomicAdd(&h[2][(u32)(key>>40)&255u],1u);
      atomicAdd(&h[3][(u32)(key>>48)&255u],1u);
    }
  }
  __syncthreads();
  for(int i=0;i<4;i++) if(h[i][tid]) atomicAdd(&hg[i*256+tid],h[i][tid]);
}

__global__ void k_prehistT(const u64* __restrict__ keys, u32* __restrict__ hg,
                           const u32* __restrict__ dCount, int cap){
  __shared__ u32 h[2][256];
  int n=(int)((*dCount)<(u32)cap?(*dCount):(u32)cap);
  int tid=threadIdx.x;
  h[0][tid]=0u; h[1][tid]=0u;
  __syncthreads();
#pragma unroll
  for(int i=0;i<4;i++){
    int p=blockIdx.x*OW_TILE+i*256+tid;
    if(p<n){
      u64 key=keys[p];
      atomicAdd(&h[0][(u32)(key>>30)&255u],1u);
      atomicAdd(&h[1][(u32)(key>>38)&255u],1u);
    }
  }
  __syncthreads();
  if(h[0][tid]) atomicAdd(&hg[tid],h[0][tid]);
  if(h[1][tid]) atomicAdd(&hg[256+tid],h[1][tid]);
}

// exclusive scan of H 256-bin histograms, one block
__global__ void k_scan256(const u32* __restrict__ hg, u32* __restrict__ gb, int H){
  __shared__ u32 sh[256];
  int t=threadIdx.x;
  for(int hh=0;hh<H;hh++){
    u32 v=hg[hh*256+t];
    sh[t]=v; __syncthreads();
    for(int o=1;o<256;o<<=1){
      u32 y=(t>=o)?sh[t-o]:0u; __syncthreads();
      sh[t]+=y; __syncthreads();
    }
    gb[hh*256+t]=sh[t]-v;
    __syncthreads();
  }
}

// ---------------- pipeline kernels ----------------
__global__ void k_edge0(const u32* __restrict__ src, const u32* __restrict__ tgt,
                        u32* cntS, u32* cntT, u64* keyA, int E){
  int j=blockIdx.x*256+threadIdx.x;
  if(j>=E) return;
  u32 s=src[j], t=tgt[j];
  atomicAdd(&cntS[s],1u); atomicAdd(&cntT[t],1u);
  keyA[j]=((u64)t<<40)|((u64)s<<24)|(u64)j;
}

__global__ void k_deg2m(const u32* __restrict__ src, const u32* __restrict__ tgt,
                        const u32* __restrict__ cntS, const u32* __restrict__ cntT,
                        u32* deg, int* scal, int E){
  __shared__ int mx;
  if(threadIdx.x==0) mx=-1;
  __syncthreads();
  int e=blockIdx.x*256+threadIdx.x;
  int loc=-1;
  if(e<E){
    u32 s=src[e], t=tgt[e];
    u32 w0=cntS[t], w2=cntT[s];
    if(w0){ atomicAdd(&deg[s],w0); loc=(int)(s>t?s:t); }
    if(w2){ atomicAdd(&deg[t],w2); if((int)t>loc) loc=(int)t; }
  }
  if(loc>=0) atomicMax(&mx,loc);
  __syncthreads();
  if(threadIdx.x==0 && mx>=0) atomicMax(&scal[S_MAXT],mx);
}

__global__ void k_degNodeHist(const u32* __restrict__ cntS, const u32* __restrict__ cntT,
                              u32* deg, u32* dh, int NN, const int* __restrict__ scal){
  int v=blockIdx.x*256+threadIdx.x;
  if(v>=NN) return;
  u32 d=deg[v]+cntS[v]*cntT[v];
  deg[v]=d;
  if(v<=scal[S_MAXT]){ if(d>65535u)d=65535u; atomicAdd(&dh[d],1u); }
}

// one block: find dstar+need from 65536-bin degree histogram
__global__ void k_dstar1b(const u32* __restrict__ dh, int* scal){
  __shared__ u32 part[256];
  __shared__ u32 sc[256];
  int t=threadIdx.x;
  long long kk=(((long long)scal[S_MAXT])+1)>>1;
  u32 s=0;
  for(int i=0;i<256;i++) s+=dh[t*256+i];
  part[t]=s; sc[t]=s; __syncthreads();
  for(int o=1;o<256;o<<=1){
    u32 y=(t>=o)?sc[t-o]:0u; __syncthreads();
    sc[t]+=y; __syncthreads();
  }
  if(kk==0){ if(t==0){ scal[S_DSTAR]=-1; scal[S_NEED]=0; } return; }
  long long cum=(long long)(sc[t]-part[t]);
  if(kk-1>=cum && kk-1<cum+(long long)part[t]){
    long long c=cum;
    for(int i=0;i<256;i++){
      u32 h=dh[t*256+i];
      if(kk-1>=c && kk-1<c+(long long)h){ scal[S_DSTAR]=t*256+i; scal[S_NEED]=(int)(kk-c); break; }
      c+=h;
    }
  }
}

__global__ void k_ef(const u32* __restrict__ deg, u32* ef, int NN, const int* __restrict__ scal){
  int v=blockIdx.x*256+threadIdx.x;
  if(v>NN) return;
  ef[v] = (v<NN && v<=scal[S_MAXT] && (int)deg[v]==scal[S_DSTAR]) ? 1u:0u;
}

__global__ void k_keep(const u32* __restrict__ deg, const u32* __restrict__ rankEq,
                       u32* keep, int NN, const int* __restrict__ scal){
  int v=blockIdx.x*256+threadIdx.x;
  if(v>=NN) return;
  int d=(int)deg[v]; int ds=scal[S_DSTAR]; int need=scal[S_NEED];
  u32 kp=1u;
  if(d<ds) kp=0u;
  else if(d==ds && (int)rankEq[v]<need) kp=0u;
  keep[v]=kp;
}

__global__ void k_keptCnt(const u32* __restrict__ src, const u32* __restrict__ tgt,
                          const u32* __restrict__ keep, u32* kc, int E){
  int j=blockIdx.x*256+threadIdx.x;
  if(j<E && keep[src[j]]) atomicAdd(&kc[tgt[j]],1u);
}

__global__ void k_cntk(const u64* __restrict__ C, const u32* __restrict__ keep,
                       const u32* __restrict__ keptCnt, u32* cntk, int E){
  int e=blockIdx.x*256+threadIdx.x;
  if(e>E) return;
  if(e==E){ cntk[e]=0u; return; }
  u64 ke=C[e];
  u32 s=(u32)(ke>>24)&0xFFFFu, te=(u32)(ke>>40);
  cntk[e]=(keep[s]&keep[te])?keptCnt[s]:0u;
}

// generate ONLY kept triplets, pre-compacted, in (e,i) order; key hs<<30|s<<15|te
__global__ void k_gen_trik(const u64* __restrict__ C, const u64* __restrict__ H,
    const u32* __restrict__ rp_tgt, const u32* __restrict__ keep,
    const u32* __restrict__ startk, u64* __restrict__ trig, int E, int cap){
  int e=blockIdx.x*256+threadIdx.x;
  if(e>=E) return;
  u32 c0=startk[e], c1=startk[e+1];
  if(c0>=c1) return;
  u64 ke=C[e];
  u32 s=(u32)(ke>>24)&0xFFFFu, te=(u32)(ke>>40);
  u32 lb=rp_tgt[s], ub=rp_tgt[s+1];
  u32 idx=c0;
  for(u32 i=lb;i<ub&&idx<c1;++i){
    u64 hk=H[i];
    u32 hsv=(u32)(hk>>24)&0xFFFFu;
    if(keep[hsv]){
      if(idx<(u32)cap) trig[idx]=((u64)hsv<<30)|((u64)s<<15)|(u64)te;
      ++idx;
    }
  }
}

__global__ void k_heads_present(const u64* __restrict__ tri, u32* __restrict__ hf,
    u32* __restrict__ present, const u32* __restrict__ dCount, int KC){
  int Tk=(int)((*dCount)<(u32)KC?(*dCount):(u32)KC);
  int q=blockIdx.x*256+threadIdx.x;
  if(q>KC) return;
  u32 f=0u;
  if(q<Tk){
    u64 key=tri[q];
    f=(q==0||(key>>30)!=(tri[q-1]>>30))?1u:0u;
    present[key>>30]=1u;
    present[(key>>15)&0x7FFFu]=1u;
    present[key&0x7FFFu]=1u;
  }
  hf[q]=f;
}

// fused: group starts (gs) + edge-index output; newid[v]=hsAll[KC+1+v]-U
__global__ void k_gs_ei(const u64* __restrict__ tri, const u32* __restrict__ hf,
    const u32* __restrict__ hsAll, u32* __restrict__ gs, float* __restrict__ out,
    int* scal, const u32* __restrict__ dCount, int KC, int out_size){
  int Tk=(int)((*dCount)<(u32)KC?(*dCount):(u32)KC);
  u32 U=hsAll[KC+1];
  int q=blockIdx.x*256+threadIdx.x;
  if(q==0){ scal[S_U]=(int)U; gs[U]=(u32)Tk; }
  if(q>=Tk) return;
  if(hf[q]) gs[hsAll[q+1]-1u]=(u32)q;
  u64 key=tri[q];
  int bs=(int)U*64;
  int i0=bs+q, i1=bs+Tk+q, i2=bs+2*Tk+q;
  if(i0<out_size) out[i0]=(float)(hsAll[(size_t)KC+1+(size_t)(key>>30)]-U);
  if(i1<out_size) out[i1]=(float)(hsAll[(size_t)KC+1+(size_t)((key>>15)&0x7FFFu)]-U);
  if(i2<out_size) out[i2]=(float)(hsAll[(size_t)KC+1+(size_t)(key&0x7FFFu)]-U);
}

// phase A: balanced 32-triplet runs; flush row-sums via atomicAdd on group change
__global__ __launch_bounds__(256) void k_xsum(const float* __restrict__ x,
    const u64* __restrict__ tri, const u32* __restrict__ hs,
    float* __restrict__ S1, float* __restrict__ S2,
    const u32* __restrict__ dCount, int KC){
  int Tk=(int)((*dCount)<(u32)KC?(*dCount):(u32)KC);
  int w=threadIdx.x>>6, lane=threadIdx.x&63;
  int r=blockIdx.x*4+w;
  int q0=r*RUN; if(q0>=Tk) return;
  int q1=q0+RUN; if(q1>Tk)q1=Tk;
  int gcur=(int)hs[q0+1]-1;
  float a1=0.f,a2=0.f;
  for(int q=q0;q<q1;q++){
    int g=(int)hs[q+1]-1;
    if(g!=gcur){
      atomicAdd(&S1[(size_t)gcur*64+lane],a1);
      atomicAdd(&S2[(size_t)gcur*64+lane],a2);
      a1=0.f;a2=0.f;gcur=g;
    }
    u64 key=tri[q];
    a1+=x[(size_t)((key>>15)&0x7FFFull)*64+lane];
    a2+=x[(size_t)(key&0x7FFFull)*64+lane];
  }
  atomicAdd(&S1[(size_t)gcur*64+lane],a1);
  atomicAdd(&S2[(size_t)gcur*64+lane],a2);
}

// phase B: per-group matvec, W in LDS (stride-65, conflict-free)
__global__ __launch_bounds__(256) void k_xmat(const float* __restrict__ x,
    const float* __restrict__ W, const float* __restrict__ b,
    const u64* __restrict__ tri, const u32* __restrict__ gs,
    const float* __restrict__ S1, const float* __restrict__ S2,
    float* __restrict__ out, const int* __restrict__ scal){
  __shared__ float Wl[192*65];
  __shared__ float sv[4][192];
  int tid=threadIdx.x;
  for(int j=tid;j<12288;j+=256){
    int r=j%192, o=j/192;      // j=(o*64+i)*3+k ; r=i*3+k
    Wl[r*65+o]=W[j];
  }
  __syncthreads();
  int U=scal[S_U];
  int w=tid>>6, lane=tid&63;
  float bv=b[lane];
  for(int g=blockIdx.x*4+w; g<U; g+=gridDim.x*4){
    u32 q0=gs[g], q1=gs[g+1];
    u32 uniq=(u32)(tri[q0]>>30);
    sv[w][lane]=x[(size_t)uniq*64+lane];
    sv[w][64+lane]=S1[(size_t)g*64+lane];
    sv[w][128+lane]=S2[(size_t)g*64+lane];
    float acc0=0.f, acc12=0.f;
#pragma unroll 4
    for(int ii=0;ii<64;ii++){
      acc0  += Wl[(ii*3+0)*65+lane]*sv[w][ii];
      acc12 += Wl[(ii*3+1)*65+lane]*sv[w][64+ii]
             + Wl[(ii*3+2)*65+lane]*sv[w][128+ii];
    }
    out[(size_t)g*64+lane] = bv + acc0 + acc12/(float)(q1-q0);
  }
}

extern "C" void kernel_launch(void* const* d_in, const int* in_sizes, int n_in,
                              void* d_out, int out_size, void* d_ws, size_t ws_size,
                              hipStream_t stream){
  const float* x = (const float*)d_in[0];
  const int*   ei = (const int*)d_in[1];
  const float* W = (const float*)d_in[2];
  const float* b = (const float*)d_in[3];
  int NN = in_sizes[0]/64;
  int E  = in_sizes[1]/2;
  const u32* src=(const u32*)ei;
  const u32* tgt=(const u32*)(ei+E);

  int KC = ((out_size/3 + OW_TILE-1)/OW_TILE)*OW_TILE; if(KC<OW_TILE) KC=OW_TILE;
  int B_E=(E+OW_TILE-1)/OW_TILE;
  int B_T=KC/OW_TILE;

  char* base=(char*)d_ws; size_t off=0;
  auto alloc=[&](size_t nInts)->u32*{
    u32* p=(u32*)(base+off);
    off += ( (nInts*4 + 255) & ~(size_t)255 );
    return p;
  };
  // ---- zero-zone (one memset) ----
  int* scal=(int*)alloc(64);
  u32* cntT=alloc(NN+1); u32* cntS=alloc(NN);
  u32* deg=alloc(NN); u32* degHist=alloc(65536);
  u32* keptCnt=alloc(NN);
  u32* histGE=alloc(4*256); u32* histGT=alloc(2*256);
  u64* descS=(u64*)alloc(2*1024);
  u64* descE=(u64*)alloc(2*(size_t)(4*B_E*256));
  u64* descT=(u64*)alloc(2*(size_t)(2*B_T*256));
  u32* hfp=alloc((size_t)KC+1+NN+1);      // [hf | present]
  float* S1=(float*)alloc((size_t)NN*64);
  float* S2=(float*)alloc((size_t)NN*64);
  size_t zoneBytes = off;
  // ---- rest (fully written before read) ----
  u64* bufA=(u64*)alloc(2*(size_t)E);
  u64* bufB=(u64*)alloc(2*(size_t)E);
  u64* bufC=(u64*)alloc(2*(size_t)E);
  u64* triA=(u64*)alloc(2*(size_t)KC); u64* triB=(u64*)alloc(2*(size_t)KC);
  u32* rp_tgt=alloc(NN+1);
  u32* cntk=alloc(E+1); u32* startk=alloc(E+1);
  u32* gbaseE=alloc(4*256); u32* gbaseT=alloc(2*256);
  u32* ef=alloc(NN+1); u32* rankEq=alloc(NN+1); u32* keep=alloc(NN);
  u32* gs=alloc(NN+2);
  u32* hsAll=alloc((size_t)KC+1+NN+1);
  if(off > ws_size) return;

  u32* hf=hfp; u32* present=hfp+(KC+1);
  const u32* dCount=startk+E;

  size_t descUsed=0;
  auto scan_ex=[&](const u32* in, u32* out, int n){
    int nb=(n+LB_TILE-1)/LB_TILE;
    scan_lb<<<nb,256,0,stream>>>(in,out,n,descS+descUsed);
    descUsed += (size_t)nb;
  };

  int gE=(E+255)/256, gE1=(E+256)/256;
  int gNN=(NN+255)/256, gNN1=(NN+256)/256;
  int gKC=(KC+255)/256, gKC1=(KC+256)/256;

  hipMemsetAsync(base,0,zoneBytes,stream);

  // edge histograms + packed key tgt<<40|src<<24|j
  k_edge0<<<gE,256,0,stream>>>(src,tgt,cntS,cntT,bufA,E);
  // degree closed form + maxT
  k_deg2m<<<gE,256,0,stream>>>(src,tgt,cntS,cntT,deg,scal,E);
  k_degNodeHist<<<gNN,256,0,stream>>>(cntS,cntT,deg,degHist,NN,scal);
  // selection: dstar/need, then keep
  k_dstar1b<<<1,256,0,stream>>>(degHist,scal);
  k_ef<<<gNN1,256,0,stream>>>(deg,ef,NN,scal);
  scan_ex(ef,rankEq,NN+1);
  k_keep<<<gNN,256,0,stream>>>(deg,rankEq,keep,NN,scal);
  k_keptCnt<<<gE,256,0,stream>>>(src,tgt,keep,keptCnt,E);
  // tgt CSR
  scan_ex(cntT,rp_tgt,NN+1);

  // 4-pass onesweep chain: passes 1-2 -> src-sorted (bufC), 3-4 -> tgt-sorted hits (bufB)
  k_prehistE<<<B_E,256,0,stream>>>(bufA,histGE,E);
  k_scan256<<<1,256,0,stream>>>(histGE,gbaseE,4);
  ow_pass<<<B_E,256,0,stream>>>(bufA,bufB,gbaseE+0*256,descE+(size_t)0*B_E*256,24,E,nullptr,0);
  ow_pass<<<B_E,256,0,stream>>>(bufB,bufC,gbaseE+1*256,descE+(size_t)1*B_E*256,32,E,nullptr,0);
  ow_pass<<<B_E,256,0,stream>>>(bufC,bufA,gbaseE+2*256,descE+(size_t)2*B_E*256,40,E,nullptr,0);
  ow_pass<<<B_E,256,0,stream>>>(bufA,bufB,gbaseE+3*256,descE+(size_t)3*B_E*256,48,E,nullptr,0);

  // kept counts / offsets, generate pre-compacted triplets
  k_cntk<<<gE1,256,0,stream>>>(bufC,keep,keptCnt,cntk,E);
  scan_ex(cntk,startk,E+1);
  k_gen_trik<<<gE,256,0,stream>>>(bufC,bufB,rp_tgt,keep,startk,triA,E,KC);

  // triplet sort by hs (2 onesweep passes)
  k_prehistT<<<B_T,256,0,stream>>>(triA,histGT,dCount,KC);
  k_scan256<<<1,256,0,stream>>>(histGT,gbaseT,2);
  ow_pass<<<B_T,256,0,stream>>>(triA,triB,gbaseT+0*256,descT+(size_t)0*B_T*256,30,-1,dCount,KC);
  ow_pass<<<B_T,256,0,stream>>>(triB,triA,gbaseT+1*256,descT+(size_t)1*B_T*256,38,-1,dCount,KC);

  // groups + presence (concatenated single scan)
  k_heads_present<<<gKC1,256,0,stream>>>(triA,hf,present,dCount,KC);
  scan_ex(hfp,hsAll,KC+1+NN+1);
  float* outF=(float*)d_out;
  k_gs_ei<<<gKC,256,0,stream>>>(triA,hf,hsAll,gs,outF,scal,dCount,KC,out_size);

  // features: balanced scatter-sum then per-group matvec
  k_xsum<<<KC/(4*RUN),256,0,stream>>>(x,triA,hsAll,S1,S2,dCount,KC);
  k_xmat<<<768,256,0,stream>>>(x,W,b,triA,gs,S1,S2,outF,scal);
}